// Round 3
// baseline (7155.528 us; speedup 1.0000x reference)
//
#include <hip/hip_runtime.h>
#include <hip/hip_bf16.h>
#include <cstdint>
#include <cstddef>

typedef __attribute__((ext_vector_type(4))) float f32x4;
typedef __attribute__((ext_vector_type(8))) __bf16 bf16x8;
typedef __attribute__((ext_vector_type(8))) unsigned short u16x8;
typedef __attribute__((ext_vector_type(4))) unsigned short u16x4;

#define B_ 256
#define T_ 512
#define I_ 128
#define H_ 1024
#define O_ 64
#define KTOT 1152          // H + I
#define RSTR 2304          // KTOT * 2 bytes, LDS row stride

__device__ inline unsigned short f2bf(float f){
  unsigned u = __builtin_bit_cast(unsigned, f);
  u += 0x7fffu + ((u >> 16) & 1u);          // RNE
  return (unsigned short)(u >> 16);
}
__device__ inline float bf2f(unsigned short s){
  unsigned u = ((unsigned)s) << 16;
  return __builtin_bit_cast(float, u);
}

__global__ void cast_h0(const float* __restrict__ in, unsigned short* __restrict__ out){
  int i = (blockIdx.x * 256 + threadIdx.x) * 4;   // 256 blocks -> 262144 elems exactly
  f32x4 v = *reinterpret_cast<const f32x4*>(in + i);
  u16x4 o;
  #pragma unroll
  for (int k = 0; k < 4; ++k) o[k] = f2bf(v[k]);
  *reinterpret_cast<u16x4*>(out + i) = o;
}

__device__ inline void gload_lds16(const unsigned short* src, void* dst){
  __builtin_amdgcn_global_load_lds(
      (const __attribute__((address_space(1))) unsigned int*)src,
      (__attribute__((address_space(3))) unsigned int*)dst, 16, 0, 0);
}

// Persistent cooperative fused RNN. grid=256 (8 batch-groups x 32 j-slices), block=256.
// LDS: sU [32 x 1152 bf16] = [U|W] slice (swizzled, resident)      72 KB
//      sA [32 x 1152 bf16] = [h_t | x_t] stage (swizzled)          72 KB
//      sT [32 x 32 bf16]   = h tile transpose buffer                2 KB
__global__ __launch_bounds__(256, 1) void rnn_fused(
    const float* __restrict__ X, const float* __restrict__ U, const float* __restrict__ W,
    const float* __restrict__ Ubias, const float* __restrict__ V, const float* __restrict__ Vbias,
    unsigned short* __restrict__ hbuf,   // 2 x B x H bf16
    float* __restrict__ Yp,              // 2 x 256 x 32 x 64 f32 partials
    float* __restrict__ Y,               // B x T x O
    float* __restrict__ hlast,           // B x H
    unsigned* __restrict__ bars){
  extern __shared__ char smem[];
  char* sUb = smem;                // 73728 B
  char* sAb = smem + 73728;        // 73728 B
  char* sTb = smem + 147456;       // 2048 B

  const int tid = threadIdx.x;
  const int wid = tid >> 6, lane = tid & 63;
  const int la = lane & 15, lg = lane >> 4;
  const int bg = blockIdx.x & 7, ns = blockIdx.x >> 3;
  const int b0 = bg * 32, j0 = ns * 32;

  // ---- preload [U|W] slice rows [j0,j0+32), fp32 -> bf16, swizzled ----
  for (int it = 0; it < 18; ++it){
    int c  = it * 256 + tid;          // 4608 chunks of 8 elems
    int r  = c / 144, cc = c % 144;
    const float* src = (cc < 128) ? (U + (size_t)(j0 + r) * H_ + cc * 8)
                                  : (W + (size_t)(j0 + r) * I_ + (cc - 128) * 8);
    f32x4 f0 = *reinterpret_cast<const f32x4*>(src);
    f32x4 f1 = *reinterpret_cast<const f32x4*>(src + 4);
    u16x8 o;
    #pragma unroll
    for (int k = 0; k < 4; ++k){ o[k] = f2bf(f0[k]); o[k + 4] = f2bf(f1[k]); }
    int boff = r * RSTR + ((cc * 16) ^ ((r & 7) << 4));
    *reinterpret_cast<u16x8*>(sUb + boff) = o;
  }

  // wave roles for the big MFMA: out tile (b 16 x j 16), mw = b-half, nw = j-half
  const int mw = wid & 1, nw = wid >> 1;
  const int rowA = (mw * 16 + la) * RSTR;
  const int rowB = (nw * 16 + la) * RSTR;
  const int sw   = (la & 7) << 4;           // (row&7)<<4 for both (rows = 16*h + la)
  const int cA   = (lg * 16) ^ sw;          // column part incl. swizzle
  const int jme  = j0 + nw * 16 + la;
  const float ubv = Ubias[jme];

  // V fragments (resident in regs): wave covers o-tiles {opair*2, opair*2+1}
  const int opair = nw;
  bf16x8 vfr[2];
  #pragma unroll
  for (int ot = 0; ot < 2; ++ot){
    const float* vs = V + (size_t)((opair * 2 + ot) * 16 + la) * H_ + j0 + lg * 8;
    f32x4 f0 = *reinterpret_cast<const f32x4*>(vs);
    f32x4 f1 = *reinterpret_cast<const f32x4*>(vs + 4);
    u16x8 o;
    #pragma unroll
    for (int k = 0; k < 4; ++k){ o[k] = f2bf(f0[k]); o[k + 4] = f2bf(f1[k]); }
    vfr[ot] = __builtin_bit_cast(bf16x8, o);
  }

  unsigned* cnt = bars + (size_t)bg * 64;   // 256B stride per group
  unsigned* gen = cnt + 32;

  __syncthreads();   // sU ready

  for (int t = 0; t < T_; ++t){
    const unsigned short* cur = hbuf + (size_t)(t & 1) * (B_ * H_);
    unsigned short*       nxt = hbuf + (size_t)((t + 1) & 1) * (B_ * H_);

    // ---- stage h (global bf16 -> LDS, linear dest, pre-swizzled source) ----
    #pragma unroll
    for (int it = 0; it < 16; ++it){
      int q    = it * 4 + wid;              // 64 chunks of 1KB
      int row  = q >> 1, half = q & 1;
      int swr  = (row & 7) << 4;
      int cb   = half * 1024 + lane * 16;   // linear byte within h-part of row
      int se   = (b0 + row) * H_ + (((cb ^ swr)) >> 1);
      gload_lds16(cur + se, sAb + row * RSTR + half * 1024);
    }
    // ---- stage x_t (f32 -> bf16 -> LDS row tails, swizzled write) ----
    {
      int r = tid >> 3, sub = tid & 7;
      int swr = (r & 7) << 4;
      const float* xs = X + ((size_t)(b0 + r) * T_ + t) * I_ + sub * 16;
      f32x4 a0 = *reinterpret_cast<const f32x4*>(xs);
      f32x4 a1 = *reinterpret_cast<const f32x4*>(xs + 4);
      f32x4 a2 = *reinterpret_cast<const f32x4*>(xs + 8);
      f32x4 a3 = *reinterpret_cast<const f32x4*>(xs + 12);
      u16x8 o01, o23;
      #pragma unroll
      for (int k = 0; k < 4; ++k){
        o01[k] = f2bf(a0[k]); o01[k + 4] = f2bf(a1[k]);
        o23[k] = f2bf(a2[k]); o23[k + 4] = f2bf(a3[k]);
      }
      int cb = sub * 32;
      *reinterpret_cast<u16x8*>(sAb + r * RSTR + 2048 + (cb ^ swr))        = o01;
      *reinterpret_cast<u16x8*>(sAb + r * RSTR + 2048 + ((cb + 16) ^ swr)) = o23;
    }
    __syncthreads();   // staging complete (drains vmcnt)

    // ---- pre-activation: [h|x] . [U|W]^T, K = 1152 ----
    f32x4 acc0 = {0, 0, 0, 0}, acc1 = {0, 0, 0, 0};
    #pragma unroll
    for (int ks = 0; ks < 36; ++ks){
      bf16x8 a = *reinterpret_cast<const bf16x8*>(sAb + rowA + ((ks * 64) ^ cA));
      bf16x8 b = *reinterpret_cast<const bf16x8*>(sUb + rowB + ((ks * 64) ^ cA));
      if (ks & 1) acc1 = __builtin_amdgcn_mfma_f32_16x16x32_bf16(a, b, acc1, 0, 0, 0);
      else        acc0 = __builtin_amdgcn_mfma_f32_16x16x32_bf16(a, b, acc0, 0, 0, 0);
    }

    // ---- tanh epilogue: write h to hbuf (global) and sT (LDS transpose buf) ----
    const int jl = nw * 16 + la;
    #pragma unroll
    for (int v = 0; v < 4; ++v){
      int b = mw * 16 + lg * 4 + v;         // local batch row
      float pre = acc0[v] + acc1[v] + ubv;
      float hv  = tanhf(pre);
      unsigned short hb = f2bf(hv);
      nxt[(size_t)(b0 + b) * H_ + jme] = hb;
      if (t == T_ - 1) hlast[(size_t)(b0 + b) * H_ + jme] = hv;
      *reinterpret_cast<unsigned short*>(sTb + b * 64 + ((jl * 2) ^ ((b & 3) << 4))) = hb;
    }
    __syncthreads();   // sT ready

    // ---- V partial: Yp_block[32b x 64o] = h_tile[32b x 32j] . Vslice^T ----
    {
      int bb = mw * 16 + la;
      bf16x8 hfr = *reinterpret_cast<const bf16x8*>(sTb + bb * 64 + ((lg * 16) ^ ((bb & 3) << 4)));
      f32x4 y0 = {0, 0, 0, 0}, y1 = {0, 0, 0, 0};
      y0 = __builtin_amdgcn_mfma_f32_16x16x32_bf16(hfr, vfr[0], y0, 0, 0, 0);
      y1 = __builtin_amdgcn_mfma_f32_16x16x32_bf16(hfr, vfr[1], y1, 0, 0, 0);
      float* yp = Yp + (size_t)(t & 1) * (256 * 2048) + (size_t)blockIdx.x * 2048;
      #pragma unroll
      for (int v = 0; v < 4; ++v){
        int b = mw * 16 + lg * 4 + v;
        yp[b * 64 + (opair * 2) * 16 + la]     = y0[v];
        yp[b * 64 + (opair * 2 + 1) * 16 + la] = y1[v];
      }
    }
    __syncthreads();   // all global writes of this block drained

    // ---- group barrier (32 blocks sharing bg), agent-scope release/acquire ----
    if (tid == 0){
      unsigned g = __hip_atomic_load(gen, __ATOMIC_RELAXED, __HIP_MEMORY_SCOPE_AGENT);
      unsigned a = __hip_atomic_fetch_add(cnt, 1u, __ATOMIC_ACQ_REL, __HIP_MEMORY_SCOPE_AGENT);
      if (a == 31u){
        __hip_atomic_store(cnt, 0u, __ATOMIC_RELAXED, __HIP_MEMORY_SCOPE_AGENT);
        __hip_atomic_store(gen, g + 1u, __ATOMIC_RELEASE, __HIP_MEMORY_SCOPE_AGENT);
      } else {
        while (__hip_atomic_load(gen, __ATOMIC_RELAXED, __HIP_MEMORY_SCOPE_AGENT) == g)
          __builtin_amdgcn_s_sleep(2);
        __builtin_amdgcn_fence(__ATOMIC_ACQUIRE, "agent");
      }
    }
    __syncthreads();

    // ---- reduce this block's share: batch row ns, all 64 o ----
    if (tid < 64){
      float accY = Vbias[tid];
      const float* base = Yp + (size_t)(t & 1) * (256 * 2048) + (size_t)bg * 2048 + ns * 64 + tid;
      #pragma unroll 8
      for (int s = 0; s < 32; ++s) accY += base[(size_t)s * 8 * 2048];
      Y[((size_t)(b0 + ns) * T_ + t) * O_ + tid] = accY;
    }
  }
}

extern "C" void kernel_launch(void* const* d_in, const int* in_sizes, int n_in,
                              void* d_out, int out_size, void* d_ws, size_t ws_size,
                              hipStream_t stream){
  const float* X  = (const float*)d_in[0];
  const float* h0 = (const float*)d_in[1];
  const float* W  = (const float*)d_in[2];
  const float* U  = (const float*)d_in[3];
  const float* Ub = (const float*)d_in[4];
  const float* V  = (const float*)d_in[5];
  const float* Vb = (const float*)d_in[6];
  float* Y     = (float*)d_out;
  float* hlast = Y + (size_t)B_ * T_ * O_;

  char* ws = (char*)d_ws;
  unsigned short* hbuf = (unsigned short*)(ws);              // 1,048,576 B
  float*          Yp   = (float*)(ws + 1048576);             // 4,194,304 B
  unsigned*       bars = (unsigned*)(ws + 5242880);          // 2,048 B   -> total ~5.2 MB

  cast_h0<<<256, 256, 0, stream>>>(h0, hbuf);                // hbuf[0] = bf16(h0)
  (void)hipMemsetAsync(bars, 0, 2048, stream);

  (void)hipFuncSetAttribute((const void*)rnn_fused,
                            hipFuncAttributeMaxDynamicSharedMemorySize, 149504);
  void* args[] = { (void*)&X, (void*)&U, (void*)&W, (void*)&Ub, (void*)&V, (void*)&Vb,
                   (void*)&hbuf, (void*)&Yp, (void*)&Y, (void*)&hlast, (void*)&bars };
  (void)hipLaunchCooperativeKernel((const void*)rnn_fused, dim3(256), dim3(256),
                                   args, 149504, stream);
}

// Round 4
// 3288.210 us; speedup vs baseline: 2.1761x; 2.1761x over previous
//
#include <hip/hip_runtime.h>
#include <hip/hip_bf16.h>
#include <cstdint>
#include <cstddef>

typedef __attribute__((ext_vector_type(4))) float f32x4;
typedef __attribute__((ext_vector_type(8))) __bf16 bf16x8;
typedef __attribute__((ext_vector_type(8))) unsigned short u16x8;
typedef __attribute__((ext_vector_type(4))) unsigned short u16x4;

#define B_ 256
#define T_ 512
#define I_ 128
#define H_ 1024
#define O_ 64
#define KTOT 1152          // H + I
#define RSTR 2304          // KTOT * 2 bytes, LDS row stride

__device__ inline unsigned short f2bf(float f){
  unsigned u = __builtin_bit_cast(unsigned, f);
  u += 0x7fffu + ((u >> 16) & 1u);          // RNE
  return (unsigned short)(u >> 16);
}

__global__ void cast_h0(const float* __restrict__ in, unsigned short* __restrict__ out){
  int i = (blockIdx.x * 256 + threadIdx.x) * 4;   // 256 blocks -> 262144 elems exactly
  f32x4 v = *reinterpret_cast<const f32x4*>(in + i);
  u16x4 o;
  #pragma unroll
  for (int k = 0; k < 4; ++k) o[k] = f2bf(v[k]);
  *reinterpret_cast<u16x4*>(out + i) = o;
}

// global->LDS direct, reading from the device coherence point (sc0|sc1 = 17)
__device__ inline void gload_lds16_llc(const unsigned short* src, void* dst){
  __builtin_amdgcn_global_load_lds(
      (const __attribute__((address_space(1))) unsigned int*)src,
      (__attribute__((address_space(3))) unsigned int*)dst, 16, 0, 17);
}

// Persistent cooperative fused RNN. grid=256 (8 batch-groups x 32 j-slices), block=256.
// Cross-block data via relaxed agent atomics (LLC-coherent, fence-free).
// LDS: sU [32 x 1152 bf16] = [U|W] slice (swizzled, resident)      72 KB
//      sA [32 x 1152 bf16] = [h_t | x_t] stage (swizzled)          72 KB
//      sT [32 x 32 bf16]   = h tile transpose buffer                2 KB
__global__ __launch_bounds__(256, 1) void rnn_fused(
    const float* __restrict__ X, const float* __restrict__ U, const float* __restrict__ W,
    const float* __restrict__ Ubias, const float* __restrict__ V, const float* __restrict__ Vbias,
    unsigned short* __restrict__ hbuf,   // 2 x B x H bf16
    float* __restrict__ Yp,              // 2 x 256 x 32 x 64 f32 partials
    float* __restrict__ Y,               // B x T x O
    float* __restrict__ hlast,           // B x H
    unsigned* __restrict__ flags){       // 256 per-block step flags
  extern __shared__ char smem[];
  char* sUb = smem;                // 73728 B
  char* sAb = smem + 73728;        // 73728 B
  char* sTb = smem + 147456;       // 2048 B

  const int tid = threadIdx.x;
  const int wid = tid >> 6, lane = tid & 63;
  const int la = lane & 15, lg = lane >> 4;
  const int bg = blockIdx.x & 7, ns = blockIdx.x >> 3;
  const int b0 = bg * 32, j0 = ns * 32;

  // ---- preload [U|W] slice rows [j0,j0+32), fp32 -> bf16, swizzled ----
  for (int it = 0; it < 18; ++it){
    int c  = it * 256 + tid;          // 4608 chunks of 8 elems
    int r  = c / 144, cc = c % 144;
    const float* src = (cc < 128) ? (U + (size_t)(j0 + r) * H_ + cc * 8)
                                  : (W + (size_t)(j0 + r) * I_ + (cc - 128) * 8);
    f32x4 f0 = *reinterpret_cast<const f32x4*>(src);
    f32x4 f1 = *reinterpret_cast<const f32x4*>(src + 4);
    u16x8 o;
    #pragma unroll
    for (int k = 0; k < 4; ++k){ o[k] = f2bf(f0[k]); o[k + 4] = f2bf(f1[k]); }
    int boff = r * RSTR + ((cc * 16) ^ ((r & 7) << 4));
    *reinterpret_cast<u16x8*>(sUb + boff) = o;
  }

  // wave roles: out tile (b 16 x j 16); mw = batch half, nw = j half
  const int mw = wid & 1, nw = wid >> 1;
  const int rowA = (mw * 16 + la) * RSTR;
  const int rowB = (nw * 16 + la) * RSTR;
  const int sw   = (la & 7) << 4;
  const int cA   = (lg * 16) ^ sw;
  const int jme  = j0 + nw * 16 + la;
  const float ubv = Ubias[jme];

  // V fragments resident in regs: wave covers o-tiles {nw*2, nw*2+1} (nw in 0..1)
  const int opair = nw;
  bf16x8 vfr[2];
  #pragma unroll
  for (int ot = 0; ot < 2; ++ot){
    const float* vs = V + (size_t)((opair * 2 + ot) * 16 + la) * H_ + j0 + lg * 8;
    f32x4 f0 = *reinterpret_cast<const f32x4*>(vs);
    f32x4 f1 = *reinterpret_cast<const f32x4*>(vs + 4);
    u16x8 o;
    #pragma unroll
    for (int k = 0; k < 4; ++k){ o[k] = f2bf(f0[k]); o[k + 4] = f2bf(f1[k]); }
    vfr[ot] = __builtin_bit_cast(bf16x8, o);
  }

  __syncthreads();   // sU ready

  for (int t = 0; t < T_; ++t){
    const unsigned short* cur = hbuf + (size_t)(t & 1) * (B_ * H_);
    unsigned short*       nxt = hbuf + (size_t)((t + 1) & 1) * (B_ * H_);

    // ---- wait: all 32 writers of this bg have published h_t (flag >= t) ----
    if (tid < 32){
      while (__hip_atomic_load(&flags[bg * 32 + tid], __ATOMIC_RELAXED,
                               __HIP_MEMORY_SCOPE_AGENT) < (unsigned)t)
        __builtin_amdgcn_s_sleep(1);
    }
    __syncthreads();

    // ---- stage h (LLC -> LDS, linear dest, pre-swizzled source) ----
    #pragma unroll
    for (int it = 0; it < 16; ++it){
      int q    = it * 4 + wid;              // 64 chunks of 1KB
      int row  = q >> 1, half = q & 1;
      int swr  = (row & 7) << 4;
      int cb   = half * 1024 + lane * 16;
      int se   = (b0 + row) * H_ + (((cb ^ swr)) >> 1);
      gload_lds16_llc(cur + se, sAb + row * RSTR + half * 1024);
    }
    // ---- stage x_t (f32 -> bf16 -> LDS row tails, swizzled write) ----
    {
      int r = tid >> 3, sub = tid & 7;
      int swr = (r & 7) << 4;
      const float* xs = X + ((size_t)(b0 + r) * T_ + t) * I_ + sub * 16;
      f32x4 a0 = *reinterpret_cast<const f32x4*>(xs);
      f32x4 a1 = *reinterpret_cast<const f32x4*>(xs + 4);
      f32x4 a2 = *reinterpret_cast<const f32x4*>(xs + 8);
      f32x4 a3 = *reinterpret_cast<const f32x4*>(xs + 12);
      u16x8 o01, o23;
      #pragma unroll
      for (int k = 0; k < 4; ++k){
        o01[k] = f2bf(a0[k]); o01[k + 4] = f2bf(a1[k]);
        o23[k] = f2bf(a2[k]); o23[k + 4] = f2bf(a3[k]);
      }
      int cb = sub * 32;
      *reinterpret_cast<u16x8*>(sAb + r * RSTR + 2048 + (cb ^ swr))        = o01;
      *reinterpret_cast<u16x8*>(sAb + r * RSTR + 2048 + ((cb + 16) ^ swr)) = o23;
    }
    // ---- reduce previous step's Y partials (wave0, overlaps staging) ----
    if (t > 0 && tid < 64){
      int slot = (t - 1) & 1;
      float acc = Vbias[tid];
      const float* base = Yp + (size_t)slot * 524288 + (size_t)bg * 2048 + (size_t)ns * 64 + tid;
      #pragma unroll 8
      for (int ws2 = 0; ws2 < 32; ++ws2)
        acc += __hip_atomic_load(base + (size_t)ws2 * 16384, __ATOMIC_RELAXED,
                                 __HIP_MEMORY_SCOPE_AGENT);
      Y[((size_t)(b0 + ns) * T_ + (t - 1)) * O_ + tid] = acc;
    }
    __syncthreads();   // staging complete

    // ---- pre-activation: [h|x] . [U|W]^T, K = 1152 ----
    f32x4 acc0 = {0, 0, 0, 0}, acc1 = {0, 0, 0, 0};
    #pragma unroll
    for (int ks = 0; ks < 36; ++ks){
      bf16x8 a = *reinterpret_cast<const bf16x8*>(sAb + rowA + ((ks * 64) ^ cA));
      bf16x8 b = *reinterpret_cast<const bf16x8*>(sUb + rowB + ((ks * 64) ^ cA));
      if (ks & 1) acc1 = __builtin_amdgcn_mfma_f32_16x16x32_bf16(a, b, acc1, 0, 0, 0);
      else        acc0 = __builtin_amdgcn_mfma_f32_16x16x32_bf16(a, b, acc0, 0, 0, 0);
    }

    // ---- tanh epilogue -> sT (transpose buf); hlast on final step ----
    const int jl = nw * 16 + la;
    #pragma unroll
    for (int v = 0; v < 4; ++v){
      int b = mw * 16 + lg * 4 + v;         // local batch row
      float pre = acc0[v] + acc1[v] + ubv;
      float hv  = tanhf(pre);
      unsigned short hb = f2bf(hv);
      if (t == T_ - 1) hlast[(size_t)(b0 + b) * H_ + jme] = hv;
      *reinterpret_cast<unsigned short*>(sTb + b * 64 + ((jl * 2) ^ ((b & 3) << 4))) = hb;
    }
    __syncthreads();   // sT ready

    // ---- publish h_{t+1} (LLC atomic stores, 8B per thread from sT) ----
    {
      int br = tid >> 3, j0l = (tid & 7) * 4;
      u16x4 hv4 = *reinterpret_cast<const u16x4*>(sTb + br * 64 + ((j0l * 2) ^ ((br & 3) << 4)));
      uint64_t hp = __builtin_bit_cast(uint64_t, hv4);
      __hip_atomic_store((uint64_t*)(nxt + (size_t)(b0 + br) * H_ + j0 + j0l), hp,
                         __ATOMIC_RELAXED, __HIP_MEMORY_SCOPE_AGENT);
    }
    // ---- V partial: Yp_block[32b x 64o] = h_tile . Vslice^T (LLC atomic stores) ----
    {
      int bb = mw * 16 + la;
      bf16x8 hfr = *reinterpret_cast<const bf16x8*>(sTb + bb * 64 + ((lg * 16) ^ ((bb & 3) << 4)));
      f32x4 y0 = {0, 0, 0, 0}, y1 = {0, 0, 0, 0};
      y0 = __builtin_amdgcn_mfma_f32_16x16x32_bf16(hfr, vfr[0], y0, 0, 0, 0);
      y1 = __builtin_amdgcn_mfma_f32_16x16x32_bf16(hfr, vfr[1], y1, 0, 0, 0);
      float* yp = Yp + (size_t)(t & 1) * 524288 + (size_t)blockIdx.x * 2048;
      #pragma unroll
      for (int v = 0; v < 4; ++v){
        int b = mw * 16 + lg * 4 + v;
        __hip_atomic_store(&yp[b * 64 + opair * 32 + la],      y0[v],
                           __ATOMIC_RELAXED, __HIP_MEMORY_SCOPE_AGENT);
        __hip_atomic_store(&yp[b * 64 + opair * 32 + 16 + la], y1[v],
                           __ATOMIC_RELAXED, __HIP_MEMORY_SCOPE_AGENT);
      }
    }
    __syncthreads();   // all waves' LLC stores acked (per-wave vmcnt drained at barrier)

    if (tid == 0)
      __hip_atomic_store(&flags[blockIdx.x], (unsigned)(t + 1),
                         __ATOMIC_RELAXED, __HIP_MEMORY_SCOPE_AGENT);
  }

  // ---- final reduce: Y partials of step T-1 ----
  if (tid < 32){
    while (__hip_atomic_load(&flags[bg * 32 + tid], __ATOMIC_RELAXED,
                             __HIP_MEMORY_SCOPE_AGENT) < (unsigned)T_)
      __builtin_amdgcn_s_sleep(1);
  }
  if (tid < 64){
    int slot = (T_ - 1) & 1;
    float acc = Vbias[tid];
    const float* base = Yp + (size_t)slot * 524288 + (size_t)bg * 2048 + (size_t)ns * 64 + tid;
    #pragma unroll 8
    for (int ws2 = 0; ws2 < 32; ++ws2)
      acc += __hip_atomic_load(base + (size_t)ws2 * 16384, __ATOMIC_RELAXED,
                               __HIP_MEMORY_SCOPE_AGENT);
    Y[((size_t)(b0 + ns) * T_ + (T_ - 1)) * O_ + tid] = acc;
  }
}

extern "C" void kernel_launch(void* const* d_in, const int* in_sizes, int n_in,
                              void* d_out, int out_size, void* d_ws, size_t ws_size,
                              hipStream_t stream){
  const float* X  = (const float*)d_in[0];
  const float* h0 = (const float*)d_in[1];
  const float* W  = (const float*)d_in[2];
  const float* U  = (const float*)d_in[3];
  const float* Ub = (const float*)d_in[4];
  const float* V  = (const float*)d_in[5];
  const float* Vb = (const float*)d_in[6];
  float* Y     = (float*)d_out;
  float* hlast = Y + (size_t)B_ * T_ * O_;

  char* ws = (char*)d_ws;
  unsigned short* hbuf  = (unsigned short*)(ws);              // 1,048,576 B
  float*          Yp    = (float*)(ws + 1048576);             // 4,194,304 B
  unsigned*       flags = (unsigned*)(ws + 5242880);          // 1,024 B

  cast_h0<<<256, 256, 0, stream>>>(h0, hbuf);                 // hbuf[0] = bf16(h0)
  (void)hipMemsetAsync(flags, 0, 2048, stream);

  (void)hipFuncSetAttribute((const void*)rnn_fused,
                            hipFuncAttributeMaxDynamicSharedMemorySize, 149504);
  void* args[] = { (void*)&X, (void*)&U, (void*)&W, (void*)&Ub, (void*)&V, (void*)&Vb,
                   (void*)&hbuf, (void*)&Yp, (void*)&Y, (void*)&hlast, (void*)&flags };
  (void)hipLaunchCooperativeKernel((const void*)rnn_fused, dim3(256), dim3(256),
                                   args, 149504, stream);
}